// Round 13
// baseline (288.534 us; speedup 1.0000x reference)
//
#include <hip/hip_runtime.h>

#define NN 100000
#define EE 1600000
#define DIM 128
#define NBUCK ((NN + 255) >> 8)   // 391 buckets of 256 nodes
#define B1 128                    // bucket-pass blocks
#define CH ((EE + B1 - 1) / B1)   // 12500 edges per block
#define GBLK ((NN + 255) / 256)   // 391 gemm blocks (512 thr, 256 rows each)

typedef unsigned int u32;
typedef __attribute__((ext_vector_type(8))) short bf16x8;
typedef __attribute__((ext_vector_type(4))) float f32x4;

union U4 { uint4 u; bf16x8 h; };

__device__ __forceinline__ float lof(u32 u) { return __uint_as_float(u << 16); }
__device__ __forceinline__ float hif(u32 u) { return __uint_as_float(u & 0xffff0000u); }
__device__ __forceinline__ u32 pack_bf2(float a, float b) {
  u32 ua = __float_as_uint(a), ub = __float_as_uint(b);
  ua = (ua + 0x7fffu + ((ua >> 16) & 1u)) >> 16;
  ub = (ub + 0x7fffu + ((ub >> 16) & 1u)) & 0xffff0000u;
  return ua | ub;
}

// ---------------- pass A: per-block bucket histogram ----------------
__global__ __launch_bounds__(256) void k_hist(const int* __restrict__ dst,
                                              int* __restrict__ hist_t) {
  __shared__ int h[NBUCK];
  for (int i = threadIdx.x; i < NBUCK; i += 256) h[i] = 0;
  __syncthreads();
  int e0 = blockIdx.x * CH;
  int e1 = e0 + CH < EE ? e0 + CH : EE;
  for (int e = e0 + threadIdx.x; e < e1; e += 256)
    atomicAdd(&h[dst[e] >> 8], 1);
  __syncthreads();
  for (int i = threadIdx.x; i < NBUCK; i += 256)
    hist_t[i * B1 + blockIdx.x] = h[i];
}

// ---------------- pass B: per-bucket scan over blocks ----------------
__global__ __launch_bounds__(B1) void k_boff(const int* __restrict__ hist_t,
                                             int* __restrict__ blockoff,
                                             int* __restrict__ btot) {
  __shared__ int ps[B1];
  int j = blockIdx.x, t = threadIdx.x;
  int v = hist_t[j * B1 + t];
  ps[t] = v;
  __syncthreads();
  #pragma unroll
  for (int off = 1; off < B1; off <<= 1) {
    int u = (t >= off) ? ps[t - off] : 0;
    __syncthreads();
    ps[t] += u;
    __syncthreads();
  }
  blockoff[j * B1 + t] = ps[t] - v;
  if (t == B1 - 1) btot[j] = ps[t];
}

// ---------------- pass B2: scan bucket totals -> bbase ----------------
__global__ __launch_bounds__(512) void k_bbase(const int* __restrict__ btot,
                                               int* __restrict__ bbase) {
  __shared__ int ps[512];
  int t = threadIdx.x;
  int v = (t < NBUCK) ? btot[t] : 0;
  ps[t] = v;
  __syncthreads();
  #pragma unroll
  for (int off = 1; off < 512; off <<= 1) {
    int u = (t >= off) ? ps[t - off] : 0;
    __syncthreads();
    ps[t] += u;
    __syncthreads();
  }
  if (t < NBUCK) bbase[t] = ps[t] - v;
  if (t == 0) bbase[NBUCK] = EE;
}

// ---------------- pass C: scatter packed (src<<8|dlow) into bucket regions ----------------
__global__ __launch_bounds__(256) void k_bucket(const int* __restrict__ src,
                                                const int* __restrict__ dst,
                                                const int* __restrict__ bbase,
                                                const int* __restrict__ blockoff,
                                                u32* __restrict__ epair) {
  __shared__ int cnt[NBUCK];
  for (int i = threadIdx.x; i < NBUCK; i += 256) cnt[i] = 0;
  __syncthreads();
  int e0 = blockIdx.x * CH;
  int e1 = e0 + CH < EE ? e0 + CH : EE;
  for (int e = e0 + threadIdx.x; e < e1; e += 256) {
    int d = dst[e], s = src[e];
    int j = d >> 8;
    int loc = atomicAdd(&cnt[j], 1);
    epair[bbase[j] + blockoff[j * B1 + blockIdx.x] + loc] =
        ((u32)s << 8) | (u32)(d & 255);
  }
}

// ---------------- pass D: per-bucket deg/ds/rp + fine scatter -> esrc ----------------
__global__ __launch_bounds__(256) void k_fine(const u32* __restrict__ epair,
                                              const int* __restrict__ bbase,
                                              int* __restrict__ rp,
                                              float* __restrict__ ds,
                                              int* __restrict__ esrc) {
  __shared__ int cntA[256], cntB[256], rpl[256], ps[256];
  int j = blockIdx.x, t = threadIdx.x;
  int node0 = j << 8;
  int e0 = bbase[j], e1 = bbase[j + 1];
  cntA[t] = 0;
  cntB[t] = 0;
  __syncthreads();
  for (int e = e0 + t; e < e1; e += 256)
    atomicAdd(&cntA[epair[e] & 255], 1);
  __syncthreads();
  int deg = cntA[t];
  ps[t] = deg;
  __syncthreads();
  #pragma unroll
  for (int off = 1; off < 256; off <<= 1) {
    int u = (t >= off) ? ps[t - off] : 0;
    __syncthreads();
    ps[t] += u;
    __syncthreads();
  }
  rpl[t] = e0 + ps[t] - deg;
  __syncthreads();
  int node = node0 + t;
  if (node < NN) {
    rp[node] = rpl[t];
    ds[node] = rsqrtf(fmaxf((float)deg, 1.0f));
  }
  if (j == 0 && t == 0) { rp[NN] = EE; ds[NN] = 0.f; }  // ds[NN]=0 zeroes sentinel gathers
  for (int e = e0 + t; e < e1; e += 256) {
    u32 pv = epair[e];
    int d = pv & 255;
    int pos = rpl[d] + atomicAdd(&cntB[d], 1);
    esrc[pos] = (int)(pv >> 8);
  }
}

// ---------------- prep: X0b table + folded Wf ----------------
// h = X0(W0-W2) + X1*W1 + Z*(-2*W2), Z = ds*sum(ds*X1)  -> fold into Wf phases.
__global__ void k_prep(const float* __restrict__ feature,
                       u32* __restrict__ X0b,
                       const float* __restrict__ W, u32* __restrict__ Wf) {
  int i = blockIdx.x * blockDim.x + threadIdx.x;
  if (i < 96 * 256) {
    // Wf u32 index = ((phase*4+ks)*8+nj)*256 + lane*4 + j
    int fi = i >> 8;
    int lane = (i >> 2) & 63;
    int jj = i & 3;
    int phase = fi >> 5, ks = (fi >> 3) & 3, nj = fi & 7;
    int g = lane >> 4, l15 = lane & 15;
    int nn = nj * 16 + l15;
    int ku = phase * 64 + ks * 16 + g * 4 + jj;
    int k = ku * 2;
    float a0 = W[(size_t)k * 128 + nn];
    float a1 = W[(size_t)(k + 1) * 128 + nn];
    if (phase == 0) {
      a0 -= W[(size_t)(k + 256) * 128 + nn];
      a1 -= W[(size_t)(k + 257) * 128 + nn];
    } else if (phase == 2) {
      a0 *= -2.0f;
      a1 *= -2.0f;
    }
    Wf[i] = pack_bf2(a0, a1);
  }
  const int total = NN * 32;  // uint2 count (4 dims each)
  int st = gridDim.x * blockDim.x;
  for (int j = i; j < total; j += st) {
    int n = j >> 5;
    float4 f = *(const float4*)(feature + (size_t)n * DIM + (j & 31) * 4);
    ((uint2*)X0b)[j] = make_uint2(pack_bf2(f.x, f.y), pack_bf2(f.z, f.w));
  }
}

// ---------------- prop1: X1 = -ds[n]*sum ds[s]*X0[s] ----------------
// Wide gather (dwordx4/lane, 4 edges per wave-instruction), sentinel-select
// tails (ds[NN]=0), shfl_xor combine. Props at random-gather BW floor (R8-R10).
__global__ __launch_bounds__(256) void k_prop1(const u32* __restrict__ X0b,
                                               const float* __restrict__ ds,
                                               const int* __restrict__ rp,
                                               const int* __restrict__ esrc,
                                               u32* __restrict__ X1b) {
  int n = blockIdx.x * 4 + (threadIdx.x >> 6);
  int lane = threadIdx.x & 63;
  int grp = lane >> 4, l15 = lane & 15;
  int beg = rp[n], end = rp[n + 1];
  float axA[4], ayA[4], axB[4], ayB[4];
  #pragma unroll
  for (int i = 0; i < 4; ++i) { axA[i] = 0.f; ayA[i] = 0.f; axB[i] = 0.f; ayB[i] = 0.f; }
  for (int p = beg; p < end; p += 8) {
    int qA = p + grp, qB = p + 4 + grp;
    int evA = esrc[qA];            // unconditional (esrc padded)
    int evB = esrc[qB];
    int sA = (qA < end) ? evA : NN;  // register select, no branch
    int sB = (qB < end) ? evB : NN;
    uint4 uA = *(const uint4*)(X0b + (size_t)sA * 64 + l15 * 4);
    uint4 uB = *(const uint4*)(X0b + (size_t)sB * 64 + l15 * 4);
    float dvA = ds[sA];
    float dvB = ds[sB];
    axA[0] = fmaf(lof(uA.x), dvA, axA[0]); ayA[0] = fmaf(hif(uA.x), dvA, ayA[0]);
    axA[1] = fmaf(lof(uA.y), dvA, axA[1]); ayA[1] = fmaf(hif(uA.y), dvA, ayA[1]);
    axA[2] = fmaf(lof(uA.z), dvA, axA[2]); ayA[2] = fmaf(hif(uA.z), dvA, ayA[2]);
    axA[3] = fmaf(lof(uA.w), dvA, axA[3]); ayA[3] = fmaf(hif(uA.w), dvA, ayA[3]);
    axB[0] = fmaf(lof(uB.x), dvB, axB[0]); ayB[0] = fmaf(hif(uB.x), dvB, ayB[0]);
    axB[1] = fmaf(lof(uB.y), dvB, axB[1]); ayB[1] = fmaf(hif(uB.y), dvB, ayB[1]);
    axB[2] = fmaf(lof(uB.z), dvB, axB[2]); ayB[2] = fmaf(hif(uB.z), dvB, ayB[2]);
    axB[3] = fmaf(lof(uB.w), dvB, axB[3]); ayB[3] = fmaf(hif(uB.w), dvB, ayB[3]);
  }
  float v[8];
  #pragma unroll
  for (int i = 0; i < 4; ++i) {
    v[2 * i] = axA[i] + axB[i];
    v[2 * i + 1] = ayA[i] + ayB[i];
  }
  #pragma unroll
  for (int i = 0; i < 8; ++i) {
    v[i] += __shfl_xor(v[i], 16);
    v[i] += __shfl_xor(v[i], 32);
  }
  if (grp == 0) {
    float dsn = ds[n];
    uint4 o;
    o.x = pack_bf2(-dsn * v[0], -dsn * v[1]);
    o.y = pack_bf2(-dsn * v[2], -dsn * v[3]);
    o.z = pack_bf2(-dsn * v[4], -dsn * v[5]);
    o.w = pack_bf2(-dsn * v[6], -dsn * v[7]);
    *(uint4*)(X1b + (size_t)n * 64 + l15 * 4) = o;
  }
}

// ---------------- prop2: Z = ds[n]*sum X1[s]*ds[s] (X0-term folded into Wf) ----
__global__ __launch_bounds__(256) void k_prop2(const u32* __restrict__ X1b,
                                               const float* __restrict__ ds,
                                               const int* __restrict__ rp,
                                               const int* __restrict__ esrc,
                                               u32* __restrict__ Zb) {
  int n = blockIdx.x * 4 + (threadIdx.x >> 6);
  int lane = threadIdx.x & 63;
  int grp = lane >> 4, l15 = lane & 15;
  int beg = rp[n], end = rp[n + 1];
  float axA[4], ayA[4], axB[4], ayB[4];
  #pragma unroll
  for (int i = 0; i < 4; ++i) { axA[i] = 0.f; ayA[i] = 0.f; axB[i] = 0.f; ayB[i] = 0.f; }
  for (int p = beg; p < end; p += 8) {
    int qA = p + grp, qB = p + 4 + grp;
    int evA = esrc[qA];
    int evB = esrc[qB];
    int sA = (qA < end) ? evA : NN;
    int sB = (qB < end) ? evB : NN;
    uint4 uA = *(const uint4*)(X1b + (size_t)sA * 64 + l15 * 4);
    uint4 uB = *(const uint4*)(X1b + (size_t)sB * 64 + l15 * 4);
    float dvA = ds[sA];
    float dvB = ds[sB];
    axA[0] = fmaf(lof(uA.x), dvA, axA[0]); ayA[0] = fmaf(hif(uA.x), dvA, ayA[0]);
    axA[1] = fmaf(lof(uA.y), dvA, axA[1]); ayA[1] = fmaf(hif(uA.y), dvA, ayA[1]);
    axA[2] = fmaf(lof(uA.z), dvA, axA[2]); ayA[2] = fmaf(hif(uA.z), dvA, ayA[2]);
    axA[3] = fmaf(lof(uA.w), dvA, axA[3]); ayA[3] = fmaf(hif(uA.w), dvA, ayA[3]);
    axB[0] = fmaf(lof(uB.x), dvB, axB[0]); ayB[0] = fmaf(hif(uB.x), dvB, ayB[0]);
    axB[1] = fmaf(lof(uB.y), dvB, axB[1]); ayB[1] = fmaf(hif(uB.y), dvB, ayB[1]);
    axB[2] = fmaf(lof(uB.z), dvB, axB[2]); ayB[2] = fmaf(hif(uB.z), dvB, ayB[2]);
    axB[3] = fmaf(lof(uB.w), dvB, axB[3]); ayB[3] = fmaf(hif(uB.w), dvB, ayB[3]);
  }
  float v[8];
  #pragma unroll
  for (int i = 0; i < 4; ++i) {
    v[2 * i] = axA[i] + axB[i];
    v[2 * i + 1] = ayA[i] + ayB[i];
  }
  #pragma unroll
  for (int i = 0; i < 8; ++i) {
    v[i] += __shfl_xor(v[i], 16);
    v[i] += __shfl_xor(v[i], 32);
  }
  if (grp == 0) {
    float dsn = ds[n];
    uint4 o;
    o.x = pack_bf2(dsn * v[0], dsn * v[1]);
    o.y = pack_bf2(dsn * v[2], dsn * v[3]);
    o.z = pack_bf2(dsn * v[4], dsn * v[5]);
    o.w = pack_bf2(dsn * v[6], dsn * v[7]);
    *(uint4*)(Zb + (size_t)n * 64 + l15 * 4) = o;
  }
}

// ---------------- MFMA GEMM: 512 thr, 32KB per-phase LDS -> 4 blocks/CU ----
__global__ __launch_bounds__(512) void k_gemm(const u32* __restrict__ X0b,
                                              const u32* __restrict__ X1b,
                                              const u32* __restrict__ Zb,
                                              const u32* __restrict__ Wf,
                                              const float* __restrict__ bias,
                                              const float* __restrict__ snorm,
                                              float* __restrict__ out,
                                              float* __restrict__ gsum_part,
                                              float* __restrict__ gsq_part) {
  __shared__ u32 wlds[8192];   // 32 KB: one phase of Wf
  __shared__ float ls[256];
  int tid = threadIdx.x;
  int wid = tid >> 6, lane = tid & 63;
  int l15 = lane & 15, g = lane >> 4;
  int row0 = blockIdx.x * 256 + wid * 32;
  bool active = (row0 + 32) <= NN;
  if (!active) row0 = 0;

  size_t rb0 = (size_t)(row0 + l15) * 64 + g * 4;
  size_t rb1 = rb0 + (size_t)16 * 64;

  f32x4 acc[2][8];
  #pragma unroll
  for (int mi = 0; mi < 2; ++mi)
    #pragma unroll
    for (int nj = 0; nj < 8; ++nj) acc[mi][nj] = (f32x4){0.f, 0.f, 0.f, 0.f};

  const u32* tabs[3] = {X0b, X1b, Zb};
  #pragma unroll
  for (int phase = 0; phase < 3; ++phase) {
    __syncthreads();
    #pragma unroll
    for (int l = 0; l < 4; ++l)
      ((uint4*)wlds)[tid + l * 512] =
          ((const uint4*)Wf)[phase * 2048 + tid + l * 512];
    __syncthreads();
    const u32* A = tabs[phase];
    #pragma unroll
    for (int ks = 0; ks < 4; ++ks) {
      U4 a0, a1;
      a0.u = *(const uint4*)(A + rb0 + ks * 16);
      a1.u = *(const uint4*)(A + rb1 + ks * 16);
      #pragma unroll
      for (int nj = 0; nj < 8; ++nj) {
        U4 b;
        b.u = ((const uint4*)wlds)[(ks * 8 + nj) * 64 + lane];
        acc[0][nj] = __builtin_amdgcn_mfma_f32_16x16x32_bf16(a0.h, b.h, acc[0][nj], 0, 0, 0);
        acc[1][nj] = __builtin_amdgcn_mfma_f32_16x16x32_bf16(a1.h, b.h, acc[1][nj], 0, 0, 0);
      }
    }
  }

  float cs[8], cq[8];
  #pragma unroll
  for (int nj = 0; nj < 8; ++nj) { cs[nj] = 0.f; cq[nj] = 0.f; }
  if (active) {
    float bs[8];
    #pragma unroll
    for (int nj = 0; nj < 8; ++nj) bs[nj] = bias[nj * 16 + l15];
    #pragma unroll
    for (int mi = 0; mi < 2; ++mi) {
      #pragma unroll
      for (int r = 0; r < 4; ++r) {
        int row = row0 + mi * 16 + g * 4 + r;
        float sn = snorm[row];
        #pragma unroll
        for (int nj = 0; nj < 8; ++nj) {
          float h = (acc[mi][nj][r] + bs[nj]) * sn;
          out[(size_t)row * DIM + nj * 16 + l15] = h;
          cs[nj] += h;
          cq[nj] += h * h;
        }
      }
    }
  }
  if (tid < 256) ls[tid] = 0.f;
  __syncthreads();
  if (active) {
    #pragma unroll
    for (int nj = 0; nj < 8; ++nj) {
      atomicAdd(&ls[nj * 16 + l15], cs[nj]);      // LDS atomics only
      atomicAdd(&ls[128 + nj * 16 + l15], cq[nj]);
    }
  }
  __syncthreads();
  if (tid < 128) {  // plain stores -- no global atomics
    gsum_part[(size_t)blockIdx.x * 128 + tid] = ls[tid];
    gsq_part[(size_t)blockIdx.x * 128 + tid] = ls[128 + tid];
  }
}

// ---------------- reduce partials -> scale/shift ----------------
__global__ __launch_bounds__(128) void k_bnprep(const float* __restrict__ gsum_part,
                                                const float* __restrict__ gsq_part,
                                                const float* __restrict__ gamma,
                                                const float* __restrict__ beta,
                                                float* __restrict__ scale,
                                                float* __restrict__ shift) {
  int c = threadIdx.x;
  float s = 0.f, q = 0.f;
  for (int j = 0; j < GBLK; ++j) {
    s += gsum_part[(size_t)j * 128 + c];
    q += gsq_part[(size_t)j * 128 + c];
  }
  float m = s * (1.0f / NN);
  float var = fmaxf(q * (1.0f / NN) - m * m, 0.f);
  float sc = gamma[c] * rsqrtf(var + 1e-5f);
  scale[c] = sc;
  shift[c] = beta[c] - m * sc;
}

// ---------------- BN apply + relu (in-place on out) ----------------
__global__ __launch_bounds__(256) void k_apply(float* __restrict__ out,
                                               const float* __restrict__ scale,
                                               const float* __restrict__ shift) {
  const int total4 = NN * DIM / 4;
  int i = blockIdx.x * blockDim.x + threadIdx.x;
  int st = gridDim.x * blockDim.x;   // multiple of 32 -> (i&31) invariant
  int c4 = (i & 31) * 4;
  float4 s = *(const float4*)(scale + c4);
  float4 sh = *(const float4*)(shift + c4);
  for (int i4 = i; i4 < total4; i4 += st) {
    float4 v = ((float4*)out)[i4];
    v.x = fmaxf(fmaf(v.x, s.x, sh.x), 0.f);
    v.y = fmaxf(fmaf(v.y, s.y, sh.y), 0.f);
    v.z = fmaxf(fmaf(v.z, s.z, sh.z), 0.f);
    v.w = fmaxf(fmaf(v.w, s.w, sh.w), 0.f);
    ((float4*)out)[i4] = v;
  }
}

extern "C" void kernel_launch(void* const* d_in, const int* in_sizes, int n_in,
                              void* d_out, int out_size, void* d_ws, size_t ws_size,
                              hipStream_t stream) {
  const float* feature = (const float*)d_in[0];
  const float* snorm   = (const float*)d_in[1];
  const int*   src     = (const int*)d_in[2];
  const int*   dst     = (const int*)d_in[3];
  const float* W       = (const float*)d_in[4];
  const float* bias    = (const float*)d_in[5];
  const float* gamma   = (const float*)d_in[6];
  const float* beta    = (const float*)d_in[7];
  float* out = (float*)d_out;

  const size_t TBL = (size_t)(NN + 1) * 64 * sizeof(u32);  // 25.6 MB + sentinel row
  char* p = (char*)d_ws;
  u32* X0b = (u32*)p; p += TBL;
  u32* X1b = (u32*)p; p += TBL;   // epair (6.4 MB) aliases this until k_fine done
  u32* Zb  = (u32*)p; p += TBL;
  u32* epair = (u32*)X1b;
  u32* Wf  = (u32*)p; p += 96 * 256 * sizeof(u32);   // 98.3 KB
  int* esrc = (int*)p;    p += (size_t)(EE + 16) * 4;  // padded for batch OOB reads
  int* rp   = (int*)p;    p += ((size_t)(NN + 1) * 4 + 127) & ~(size_t)127;
  float* ds = (float*)p;  p += (size_t)(NN + 1) * 4;
  int* hist_t   = (int*)p; p += (size_t)NBUCK * B1 * 4;  // 200 KB
  int* blockoff = (int*)p; p += (size_t)NBUCK * B1 * 4;  // 200 KB
  int* btot  = (int*)p;   p += 512 * 4;
  int* bbase = (int*)p;   p += 512 * 4;
  float* gsum_part = (float*)p; p += (size_t)GBLK * 128 * 4;  // 200 KB
  float* gsq_part  = (float*)p; p += (size_t)GBLK * 128 * 4;  // 200 KB
  float* scale = (float*)p; p += 512;
  float* shift = (float*)p; p += 512;

  k_hist<<<B1, 256, 0, stream>>>(dst, hist_t);
  k_boff<<<NBUCK, B1, 0, stream>>>(hist_t, blockoff, btot);
  k_bbase<<<1, 512, 0, stream>>>(btot, bbase);
  k_bucket<<<B1, 256, 0, stream>>>(src, dst, bbase, blockoff, epair);
  k_fine<<<NBUCK, 256, 0, stream>>>(epair, bbase, rp, ds, esrc);
  k_prep<<<4096, 256, 0, stream>>>(feature, X0b, W, Wf);
  k_prop1<<<NN / 4, 256, 0, stream>>>(X0b, ds, rp, esrc, X1b);
  k_prop2<<<NN / 4, 256, 0, stream>>>(X1b, ds, rp, esrc, Zb);
  k_gemm<<<GBLK, 512, 0, stream>>>(X0b, X1b, Zb, Wf, bias, snorm, out,
                                   gsum_part, gsq_part);
  k_bnprep<<<1, 128, 0, stream>>>(gsum_part, gsq_part, gamma, beta, scale, shift);
  k_apply<<<4096, 256, 0, stream>>>(out, scale, shift);
}

// Round 14
// 261.479 us; speedup vs baseline: 1.1035x; 1.1035x over previous
//
#include <hip/hip_runtime.h>

#define NN 100000
#define EE 1600000
#define DIM 128
#define NBUCK ((NN + 255) >> 8)   // 391 buckets of 256 nodes
#define B1 128                    // bucket-pass blocks
#define CH ((EE + B1 - 1) / B1)   // 12500 edges per block
#define GBLK ((NN + 511) / 512)   // 196 gemm blocks (1024 thr, 512 rows each)

typedef unsigned int u32;
typedef __attribute__((ext_vector_type(8))) short bf16x8;
typedef __attribute__((ext_vector_type(4))) float f32x4;

union U4 { uint4 u; bf16x8 h; };

__device__ __forceinline__ float lof(u32 u) { return __uint_as_float(u << 16); }
__device__ __forceinline__ float hif(u32 u) { return __uint_as_float(u & 0xffff0000u); }
__device__ __forceinline__ u32 pack_bf2(float a, float b) {
  u32 ua = __float_as_uint(a), ub = __float_as_uint(b);
  ua = (ua + 0x7fffu + ((ua >> 16) & 1u)) >> 16;
  ub = (ub + 0x7fffu + ((ub >> 16) & 1u)) & 0xffff0000u;
  return ua | ub;
}

// ---------------- pass A: per-block bucket histogram ----------------
__global__ __launch_bounds__(256) void k_hist(const int* __restrict__ dst,
                                              int* __restrict__ hist_t) {
  __shared__ int h[NBUCK];
  for (int i = threadIdx.x; i < NBUCK; i += 256) h[i] = 0;
  __syncthreads();
  int e0 = blockIdx.x * CH;
  int e1 = e0 + CH < EE ? e0 + CH : EE;
  for (int e = e0 + threadIdx.x; e < e1; e += 256)
    atomicAdd(&h[dst[e] >> 8], 1);
  __syncthreads();
  for (int i = threadIdx.x; i < NBUCK; i += 256)
    hist_t[i * B1 + blockIdx.x] = h[i];
}

// ---------------- pass B: per-bucket scan over blocks ----------------
__global__ __launch_bounds__(B1) void k_boff(const int* __restrict__ hist_t,
                                             int* __restrict__ blockoff,
                                             int* __restrict__ btot) {
  __shared__ int ps[B1];
  int j = blockIdx.x, t = threadIdx.x;
  int v = hist_t[j * B1 + t];
  ps[t] = v;
  __syncthreads();
  #pragma unroll
  for (int off = 1; off < B1; off <<= 1) {
    int u = (t >= off) ? ps[t - off] : 0;
    __syncthreads();
    ps[t] += u;
    __syncthreads();
  }
  blockoff[j * B1 + t] = ps[t] - v;
  if (t == B1 - 1) btot[j] = ps[t];
}

// ---------------- pass B2: scan bucket totals -> bbase ----------------
__global__ __launch_bounds__(512) void k_bbase(const int* __restrict__ btot,
                                               int* __restrict__ bbase) {
  __shared__ int ps[512];
  int t = threadIdx.x;
  int v = (t < NBUCK) ? btot[t] : 0;
  ps[t] = v;
  __syncthreads();
  #pragma unroll
  for (int off = 1; off < 512; off <<= 1) {
    int u = (t >= off) ? ps[t - off] : 0;
    __syncthreads();
    ps[t] += u;
    __syncthreads();
  }
  if (t < NBUCK) bbase[t] = ps[t] - v;
  if (t == 0) bbase[NBUCK] = EE;
}

// ---------------- pass C: scatter packed (src<<8|dlow) into bucket regions ----------------
__global__ __launch_bounds__(256) void k_bucket(const int* __restrict__ src,
                                                const int* __restrict__ dst,
                                                const int* __restrict__ bbase,
                                                const int* __restrict__ blockoff,
                                                u32* __restrict__ epair) {
  __shared__ int cnt[NBUCK];
  for (int i = threadIdx.x; i < NBUCK; i += 256) cnt[i] = 0;
  __syncthreads();
  int e0 = blockIdx.x * CH;
  int e1 = e0 + CH < EE ? e0 + CH : EE;
  for (int e = e0 + threadIdx.x; e < e1; e += 256) {
    int d = dst[e], s = src[e];
    int j = d >> 8;
    int loc = atomicAdd(&cnt[j], 1);
    epair[bbase[j] + blockoff[j * B1 + blockIdx.x] + loc] =
        ((u32)s << 8) | (u32)(d & 255);
  }
}

// ---------------- pass D: per-bucket deg/ds/rp + fine scatter -> esrc ----------------
__global__ __launch_bounds__(256) void k_fine(const u32* __restrict__ epair,
                                              const int* __restrict__ bbase,
                                              int* __restrict__ rp,
                                              float* __restrict__ ds,
                                              int* __restrict__ esrc) {
  __shared__ int cntA[256], cntB[256], rpl[256], ps[256];
  int j = blockIdx.x, t = threadIdx.x;
  int node0 = j << 8;
  int e0 = bbase[j], e1 = bbase[j + 1];
  cntA[t] = 0;
  cntB[t] = 0;
  __syncthreads();
  for (int e = e0 + t; e < e1; e += 256)
    atomicAdd(&cntA[epair[e] & 255], 1);
  __syncthreads();
  int deg = cntA[t];
  ps[t] = deg;
  __syncthreads();
  #pragma unroll
  for (int off = 1; off < 256; off <<= 1) {
    int u = (t >= off) ? ps[t - off] : 0;
    __syncthreads();
    ps[t] += u;
    __syncthreads();
  }
  rpl[t] = e0 + ps[t] - deg;
  __syncthreads();
  int node = node0 + t;
  if (node < NN) {
    rp[node] = rpl[t];
    ds[node] = rsqrtf(fmaxf((float)deg, 1.0f));
  }
  if (j == 0 && t == 0) { rp[NN] = EE; ds[NN] = 0.f; }  // ds[NN]=0 zeroes sentinel gathers
  for (int e = e0 + t; e < e1; e += 256) {
    u32 pv = epair[e];
    int d = pv & 255;
    int pos = rpl[d] + atomicAdd(&cntB[d], 1);
    esrc[pos] = (int)(pv >> 8);
  }
}

// ---------------- prep: X0b table + folded Wf ----------------
// h = X0(W0-W2) + X1*W1 + Z*(-2*W2), Z = ds*sum(ds*X1)  -> fold into Wf phases.
__global__ void k_prep(const float* __restrict__ feature,
                       u32* __restrict__ X0b,
                       const float* __restrict__ W, u32* __restrict__ Wf) {
  int i = blockIdx.x * blockDim.x + threadIdx.x;
  if (i < 96 * 256) {
    // Wf u32 index = ((phase*4+ks)*8+nj)*256 + lane*4 + j
    int fi = i >> 8;
    int lane = (i >> 2) & 63;
    int jj = i & 3;
    int phase = fi >> 5, ks = (fi >> 3) & 3, nj = fi & 7;
    int g = lane >> 4, l15 = lane & 15;
    int nn = nj * 16 + l15;
    int ku = phase * 64 + ks * 16 + g * 4 + jj;
    int k = ku * 2;
    float a0 = W[(size_t)k * 128 + nn];
    float a1 = W[(size_t)(k + 1) * 128 + nn];
    if (phase == 0) {
      a0 -= W[(size_t)(k + 256) * 128 + nn];
      a1 -= W[(size_t)(k + 257) * 128 + nn];
    } else if (phase == 2) {
      a0 *= -2.0f;
      a1 *= -2.0f;
    }
    Wf[i] = pack_bf2(a0, a1);
  }
  const int total = NN * 32;  // uint2 count (4 dims each)
  int st = gridDim.x * blockDim.x;
  for (int j = i; j < total; j += st) {
    int n = j >> 5;
    float4 f = *(const float4*)(feature + (size_t)n * DIM + (j & 31) * 4);
    ((uint2*)X0b)[j] = make_uint2(pack_bf2(f.x, f.y), pack_bf2(f.z, f.w));
  }
}

// ---------------- prop1: X1 = -ds[n]*sum ds[s]*X0[s] ----------------
// Wide gather (dwordx4/lane, 4 edges per wave-instruction), sentinel-select
// tails (ds[NN]=0), shfl_xor combine. Props at random-gather BW floor (R8-R10).
__global__ __launch_bounds__(256) void k_prop1(const u32* __restrict__ X0b,
                                               const float* __restrict__ ds,
                                               const int* __restrict__ rp,
                                               const int* __restrict__ esrc,
                                               u32* __restrict__ X1b) {
  int n = blockIdx.x * 4 + (threadIdx.x >> 6);
  int lane = threadIdx.x & 63;
  int grp = lane >> 4, l15 = lane & 15;
  int beg = rp[n], end = rp[n + 1];
  float axA[4], ayA[4], axB[4], ayB[4];
  #pragma unroll
  for (int i = 0; i < 4; ++i) { axA[i] = 0.f; ayA[i] = 0.f; axB[i] = 0.f; ayB[i] = 0.f; }
  for (int p = beg; p < end; p += 8) {
    int qA = p + grp, qB = p + 4 + grp;
    int evA = esrc[qA];            // unconditional (esrc padded)
    int evB = esrc[qB];
    int sA = (qA < end) ? evA : NN;  // register select, no branch
    int sB = (qB < end) ? evB : NN;
    uint4 uA = *(const uint4*)(X0b + (size_t)sA * 64 + l15 * 4);
    uint4 uB = *(const uint4*)(X0b + (size_t)sB * 64 + l15 * 4);
    float dvA = ds[sA];
    float dvB = ds[sB];
    axA[0] = fmaf(lof(uA.x), dvA, axA[0]); ayA[0] = fmaf(hif(uA.x), dvA, ayA[0]);
    axA[1] = fmaf(lof(uA.y), dvA, axA[1]); ayA[1] = fmaf(hif(uA.y), dvA, ayA[1]);
    axA[2] = fmaf(lof(uA.z), dvA, axA[2]); ayA[2] = fmaf(hif(uA.z), dvA, ayA[2]);
    axA[3] = fmaf(lof(uA.w), dvA, axA[3]); ayA[3] = fmaf(hif(uA.w), dvA, ayA[3]);
    axB[0] = fmaf(lof(uB.x), dvB, axB[0]); ayB[0] = fmaf(hif(uB.x), dvB, ayB[0]);
    axB[1] = fmaf(lof(uB.y), dvB, axB[1]); ayB[1] = fmaf(hif(uB.y), dvB, ayB[1]);
    axB[2] = fmaf(lof(uB.z), dvB, axB[2]); ayB[2] = fmaf(hif(uB.z), dvB, ayB[2]);
    axB[3] = fmaf(lof(uB.w), dvB, axB[3]); ayB[3] = fmaf(hif(uB.w), dvB, ayB[3]);
  }
  float v[8];
  #pragma unroll
  for (int i = 0; i < 4; ++i) {
    v[2 * i] = axA[i] + axB[i];
    v[2 * i + 1] = ayA[i] + ayB[i];
  }
  #pragma unroll
  for (int i = 0; i < 8; ++i) {
    v[i] += __shfl_xor(v[i], 16);
    v[i] += __shfl_xor(v[i], 32);
  }
  if (grp == 0) {
    float dsn = ds[n];
    uint4 o;
    o.x = pack_bf2(-dsn * v[0], -dsn * v[1]);
    o.y = pack_bf2(-dsn * v[2], -dsn * v[3]);
    o.z = pack_bf2(-dsn * v[4], -dsn * v[5]);
    o.w = pack_bf2(-dsn * v[6], -dsn * v[7]);
    *(uint4*)(X1b + (size_t)n * 64 + l15 * 4) = o;
  }
}

// ---------------- prop2: Z = ds[n]*sum X1[s]*ds[s] (X0-term folded into Wf) ----
__global__ __launch_bounds__(256) void k_prop2(const u32* __restrict__ X1b,
                                               const float* __restrict__ ds,
                                               const int* __restrict__ rp,
                                               const int* __restrict__ esrc,
                                               u32* __restrict__ Zb) {
  int n = blockIdx.x * 4 + (threadIdx.x >> 6);
  int lane = threadIdx.x & 63;
  int grp = lane >> 4, l15 = lane & 15;
  int beg = rp[n], end = rp[n + 1];
  float axA[4], ayA[4], axB[4], ayB[4];
  #pragma unroll
  for (int i = 0; i < 4; ++i) { axA[i] = 0.f; ayA[i] = 0.f; axB[i] = 0.f; ayB[i] = 0.f; }
  for (int p = beg; p < end; p += 8) {
    int qA = p + grp, qB = p + 4 + grp;
    int evA = esrc[qA];
    int evB = esrc[qB];
    int sA = (qA < end) ? evA : NN;
    int sB = (qB < end) ? evB : NN;
    uint4 uA = *(const uint4*)(X1b + (size_t)sA * 64 + l15 * 4);
    uint4 uB = *(const uint4*)(X1b + (size_t)sB * 64 + l15 * 4);
    float dvA = ds[sA];
    float dvB = ds[sB];
    axA[0] = fmaf(lof(uA.x), dvA, axA[0]); ayA[0] = fmaf(hif(uA.x), dvA, ayA[0]);
    axA[1] = fmaf(lof(uA.y), dvA, axA[1]); ayA[1] = fmaf(hif(uA.y), dvA, ayA[1]);
    axA[2] = fmaf(lof(uA.z), dvA, axA[2]); ayA[2] = fmaf(hif(uA.z), dvA, ayA[2]);
    axA[3] = fmaf(lof(uA.w), dvA, axA[3]); ayA[3] = fmaf(hif(uA.w), dvA, ayA[3]);
    axB[0] = fmaf(lof(uB.x), dvB, axB[0]); ayB[0] = fmaf(hif(uB.x), dvB, ayB[0]);
    axB[1] = fmaf(lof(uB.y), dvB, axB[1]); ayB[1] = fmaf(hif(uB.y), dvB, ayB[1]);
    axB[2] = fmaf(lof(uB.z), dvB, axB[2]); ayB[2] = fmaf(hif(uB.z), dvB, ayB[2]);
    axB[3] = fmaf(lof(uB.w), dvB, axB[3]); ayB[3] = fmaf(hif(uB.w), dvB, ayB[3]);
  }
  float v[8];
  #pragma unroll
  for (int i = 0; i < 4; ++i) {
    v[2 * i] = axA[i] + axB[i];
    v[2 * i + 1] = ayA[i] + ayB[i];
  }
  #pragma unroll
  for (int i = 0; i < 8; ++i) {
    v[i] += __shfl_xor(v[i], 16);
    v[i] += __shfl_xor(v[i], 32);
  }
  if (grp == 0) {
    float dsn = ds[n];
    uint4 o;
    o.x = pack_bf2(dsn * v[0], dsn * v[1]);
    o.y = pack_bf2(dsn * v[2], dsn * v[3]);
    o.z = pack_bf2(dsn * v[4], dsn * v[5]);
    o.w = pack_bf2(dsn * v[6], dsn * v[7]);
    *(uint4*)(Zb + (size_t)n * 64 + l15 * 4) = o;
  }
}

// ---------------- MFMA GEMM (R12 structure): 1024 thr, 96KB Wf staged once ----
__global__ __launch_bounds__(1024) void k_gemm(const u32* __restrict__ X0b,
                                               const u32* __restrict__ X1b,
                                               const u32* __restrict__ Zb,
                                               const u32* __restrict__ Wf,
                                               const float* __restrict__ bias,
                                               const float* __restrict__ snorm,
                                               float* __restrict__ out,
                                               float* __restrict__ gsum_part,
                                               float* __restrict__ gsq_part) {
  __shared__ u32 wlds[24576];   // 96 KB
  __shared__ float ls[256];
  int tid = threadIdx.x;
  #pragma unroll
  for (int l = 0; l < 6; ++l) {
    int it = tid + l * 1024;
    ((uint4*)wlds)[it] = ((const uint4*)Wf)[it];
  }
  int wid = tid >> 6, lane = tid & 63;
  int l15 = lane & 15, g = lane >> 4;
  int row0 = blockIdx.x * 512 + wid * 32;
  bool active = (row0 + 32) <= NN;
  if (!active) row0 = 0;

  size_t rb0 = (size_t)(row0 + l15) * 64 + g * 4;
  size_t rb1 = rb0 + (size_t)16 * 64;

  f32x4 acc[2][8];
  #pragma unroll
  for (int mi = 0; mi < 2; ++mi)
    #pragma unroll
    for (int nj = 0; nj < 8; ++nj) acc[mi][nj] = (f32x4){0.f, 0.f, 0.f, 0.f};

  __syncthreads();

  const u32* tabs[3] = {X0b, X1b, Zb};
  #pragma unroll
  for (int phase = 0; phase < 3; ++phase) {
    const u32* A = tabs[phase];
    #pragma unroll
    for (int ks = 0; ks < 4; ++ks) {
      U4 a0, a1;
      a0.u = *(const uint4*)(A + rb0 + ks * 16);
      a1.u = *(const uint4*)(A + rb1 + ks * 16);
      #pragma unroll
      for (int nj = 0; nj < 8; ++nj) {
        U4 b;
        b.u = ((const uint4*)wlds)[((phase * 4 + ks) * 8 + nj) * 64 + lane];
        acc[0][nj] = __builtin_amdgcn_mfma_f32_16x16x32_bf16(a0.h, b.h, acc[0][nj], 0, 0, 0);
        acc[1][nj] = __builtin_amdgcn_mfma_f32_16x16x32_bf16(a1.h, b.h, acc[1][nj], 0, 0, 0);
      }
    }
  }

  float cs[8], cq[8];
  #pragma unroll
  for (int nj = 0; nj < 8; ++nj) { cs[nj] = 0.f; cq[nj] = 0.f; }
  if (active) {
    float bs[8];
    #pragma unroll
    for (int nj = 0; nj < 8; ++nj) bs[nj] = bias[nj * 16 + l15];
    #pragma unroll
    for (int mi = 0; mi < 2; ++mi) {
      #pragma unroll
      for (int r = 0; r < 4; ++r) {
        int row = row0 + mi * 16 + g * 4 + r;
        float sn = snorm[row];
        #pragma unroll
        for (int nj = 0; nj < 8; ++nj) {
          float h = (acc[mi][nj][r] + bs[nj]) * sn;
          out[(size_t)row * DIM + nj * 16 + l15] = h;
          cs[nj] += h;
          cq[nj] += h * h;
        }
      }
    }
  }
  if (tid < 256) ls[tid] = 0.f;
  __syncthreads();
  if (active) {
    #pragma unroll
    for (int nj = 0; nj < 8; ++nj) {
      atomicAdd(&ls[nj * 16 + l15], cs[nj]);      // LDS atomics only
      atomicAdd(&ls[128 + nj * 16 + l15], cq[nj]);
    }
  }
  __syncthreads();
  if (tid < 128) {  // plain stores -- no global atomics
    gsum_part[(size_t)blockIdx.x * 128 + tid] = ls[tid];
    gsq_part[(size_t)blockIdx.x * 128 + tid] = ls[128 + tid];
  }
}

// ---------------- reduce partials -> scale/shift ----------------
__global__ __launch_bounds__(128) void k_bnprep(const float* __restrict__ gsum_part,
                                                const float* __restrict__ gsq_part,
                                                const float* __restrict__ gamma,
                                                const float* __restrict__ beta,
                                                float* __restrict__ scale,
                                                float* __restrict__ shift) {
  int c = threadIdx.x;
  float s = 0.f, q = 0.f;
  for (int j = 0; j < GBLK; ++j) {
    s += gsum_part[(size_t)j * 128 + c];
    q += gsq_part[(size_t)j * 128 + c];
  }
  float m = s * (1.0f / NN);
  float var = fmaxf(q * (1.0f / NN) - m * m, 0.f);
  float sc = gamma[c] * rsqrtf(var + 1e-5f);
  scale[c] = sc;
  shift[c] = beta[c] - m * sc;
}

// ---------------- BN apply + relu (in-place on out) ----------------
__global__ __launch_bounds__(256) void k_apply(float* __restrict__ out,
                                               const float* __restrict__ scale,
                                               const float* __restrict__ shift) {
  const int total4 = NN * DIM / 4;
  int i = blockIdx.x * blockDim.x + threadIdx.x;
  int st = gridDim.x * blockDim.x;   // multiple of 32 -> (i&31) invariant
  int c4 = (i & 31) * 4;
  float4 s = *(const float4*)(scale + c4);
  float4 sh = *(const float4*)(shift + c4);
  for (int i4 = i; i4 < total4; i4 += st) {
    float4 v = ((float4*)out)[i4];
    v.x = fmaxf(fmaf(v.x, s.x, sh.x), 0.f);
    v.y = fmaxf(fmaf(v.y, s.y, sh.y), 0.f);
    v.z = fmaxf(fmaf(v.z, s.z, sh.z), 0.f);
    v.w = fmaxf(fmaf(v.w, s.w, sh.w), 0.f);
    ((float4*)out)[i4] = v;
  }
}

extern "C" void kernel_launch(void* const* d_in, const int* in_sizes, int n_in,
                              void* d_out, int out_size, void* d_ws, size_t ws_size,
                              hipStream_t stream) {
  const float* feature = (const float*)d_in[0];
  const float* snorm   = (const float*)d_in[1];
  const int*   src     = (const int*)d_in[2];
  const int*   dst     = (const int*)d_in[3];
  const float* W       = (const float*)d_in[4];
  const float* bias    = (const float*)d_in[5];
  const float* gamma   = (const float*)d_in[6];
  const float* beta    = (const float*)d_in[7];
  float* out = (float*)d_out;

  const size_t TBL = (size_t)(NN + 1) * 64 * sizeof(u32);  // 25.6 MB + sentinel row
  char* p = (char*)d_ws;
  u32* X0b = (u32*)p; p += TBL;
  u32* X1b = (u32*)p; p += TBL;   // epair (6.4 MB) aliases this until k_fine done
  u32* Zb  = (u32*)p; p += TBL;
  u32* epair = (u32*)X1b;
  u32* Wf  = (u32*)p; p += 96 * 256 * sizeof(u32);   // 98.3 KB
  int* esrc = (int*)p;    p += (size_t)(EE + 16) * 4;  // padded for batch OOB reads
  int* rp   = (int*)p;    p += ((size_t)(NN + 1) * 4 + 127) & ~(size_t)127;
  float* ds = (float*)p;  p += (size_t)(NN + 1) * 4;
  int* hist_t   = (int*)p; p += (size_t)NBUCK * B1 * 4;  // 200 KB
  int* blockoff = (int*)p; p += (size_t)NBUCK * B1 * 4;  // 200 KB
  int* btot  = (int*)p;   p += 512 * 4;
  int* bbase = (int*)p;   p += 512 * 4;
  float* gsum_part = (float*)p; p += (size_t)GBLK * 128 * 4;  // 100 KB
  float* gsq_part  = (float*)p; p += (size_t)GBLK * 128 * 4;  // 100 KB
  float* scale = (float*)p; p += 512;
  float* shift = (float*)p; p += 512;

  k_hist<<<B1, 256, 0, stream>>>(dst, hist_t);
  k_boff<<<NBUCK, B1, 0, stream>>>(hist_t, blockoff, btot);
  k_bbase<<<1, 512, 0, stream>>>(btot, bbase);
  k_bucket<<<B1, 256, 0, stream>>>(src, dst, bbase, blockoff, epair);
  k_fine<<<NBUCK, 256, 0, stream>>>(epair, bbase, rp, ds, esrc);
  k_prep<<<4096, 256, 0, stream>>>(feature, X0b, W, Wf);
  k_prop1<<<NN / 4, 256, 0, stream>>>(X0b, ds, rp, esrc, X1b);
  k_prop2<<<NN / 4, 256, 0, stream>>>(X1b, ds, rp, esrc, Zb);
  k_gemm<<<GBLK, 1024, 0, stream>>>(X0b, X1b, Zb, Wf, bias, snorm, out,
                                    gsum_part, gsq_part);
  k_bnprep<<<1, 128, 0, stream>>>(gsum_part, gsq_part, gamma, beta, scale, shift);
  k_apply<<<4096, 256, 0, stream>>>(out, scale, shift);
}

// Round 15
// 255.513 us; speedup vs baseline: 1.1292x; 1.0234x over previous
//
#include <hip/hip_runtime.h>

#define NN 100000
#define EE 1600000
#define DIM 128
#define NBUCK ((NN + 255) >> 8)   // 391 buckets of 256 nodes
#define B1 128                    // bucket-pass blocks
#define CH ((EE + B1 - 1) / B1)   // 12500 edges per block
#define GBLK ((NN + 511) / 512)   // 196 gemm blocks (1024 thr, 512 rows each)

typedef unsigned int u32;
typedef unsigned short u16;
typedef __attribute__((ext_vector_type(8))) short bf16x8;
typedef __attribute__((ext_vector_type(4))) float f32x4;

union U4 { uint4 u; bf16x8 h; };

__device__ __forceinline__ float lof(u32 u) { return __uint_as_float(u << 16); }
__device__ __forceinline__ float hif(u32 u) { return __uint_as_float(u & 0xffff0000u); }
__device__ __forceinline__ u32 pack_bf2(float a, float b) {
  u32 ua = __float_as_uint(a), ub = __float_as_uint(b);
  ua = (ua + 0x7fffu + ((ua >> 16) & 1u)) >> 16;
  ub = (ub + 0x7fffu + ((ub >> 16) & 1u)) & 0xffff0000u;
  return ua | ub;
}

// ---------------- pass A: per-block bucket histogram ----------------
__global__ __launch_bounds__(256) void k_hist(const int* __restrict__ dst,
                                              int* __restrict__ hist_t) {
  __shared__ int h[NBUCK];
  for (int i = threadIdx.x; i < NBUCK; i += 256) h[i] = 0;
  __syncthreads();
  int e0 = blockIdx.x * CH;
  int e1 = e0 + CH < EE ? e0 + CH : EE;
  for (int e = e0 + threadIdx.x; e < e1; e += 256)
    atomicAdd(&h[dst[e] >> 8], 1);
  __syncthreads();
  for (int i = threadIdx.x; i < NBUCK; i += 256)
    hist_t[i * B1 + blockIdx.x] = h[i];
}

// ---------------- pass B: per-bucket scan over blocks ----------------
__global__ __launch_bounds__(B1) void k_boff(const int* __restrict__ hist_t,
                                             int* __restrict__ blockoff,
                                             int* __restrict__ btot) {
  __shared__ int ps[B1];
  int j = blockIdx.x, t = threadIdx.x;
  int v = hist_t[j * B1 + t];
  ps[t] = v;
  __syncthreads();
  #pragma unroll
  for (int off = 1; off < B1; off <<= 1) {
    int u = (t >= off) ? ps[t - off] : 0;
    __syncthreads();
    ps[t] += u;
    __syncthreads();
  }
  blockoff[j * B1 + t] = ps[t] - v;
  if (t == B1 - 1) btot[j] = ps[t];
}

// ---------------- pass B2: scan bucket totals -> bbase ----------------
__global__ __launch_bounds__(512) void k_bbase(const int* __restrict__ btot,
                                               int* __restrict__ bbase) {
  __shared__ int ps[512];
  int t = threadIdx.x;
  int v = (t < NBUCK) ? btot[t] : 0;
  ps[t] = v;
  __syncthreads();
  #pragma unroll
  for (int off = 1; off < 512; off <<= 1) {
    int u = (t >= off) ? ps[t - off] : 0;
    __syncthreads();
    ps[t] += u;
    __syncthreads();
  }
  if (t < NBUCK) bbase[t] = ps[t] - v;
  if (t == 0) bbase[NBUCK] = EE;
}

// ---------------- pass C: scatter packed (src<<8|dlow) into bucket regions ----------------
__global__ __launch_bounds__(256) void k_bucket(const int* __restrict__ src,
                                                const int* __restrict__ dst,
                                                const int* __restrict__ bbase,
                                                const int* __restrict__ blockoff,
                                                u32* __restrict__ epair) {
  __shared__ int cnt[NBUCK];
  for (int i = threadIdx.x; i < NBUCK; i += 256) cnt[i] = 0;
  __syncthreads();
  int e0 = blockIdx.x * CH;
  int e1 = e0 + CH < EE ? e0 + CH : EE;
  for (int e = e0 + threadIdx.x; e < e1; e += 256) {
    int d = dst[e], s = src[e];
    int j = d >> 8;
    int loc = atomicAdd(&cnt[j], 1);
    epair[bbase[j] + blockoff[j * B1 + blockIdx.x] + loc] =
        ((u32)s << 8) | (u32)(d & 255);
  }
}

// ---------------- pass D: per-bucket deg/ds/rp + fine scatter -> esrc ----------------
__global__ __launch_bounds__(256) void k_fine(const u32* __restrict__ epair,
                                              const int* __restrict__ bbase,
                                              int* __restrict__ rp,
                                              float* __restrict__ ds,
                                              int* __restrict__ esrc) {
  __shared__ int cntA[256], cntB[256], rpl[256], ps[256];
  int j = blockIdx.x, t = threadIdx.x;
  int node0 = j << 8;
  int e0 = bbase[j], e1 = bbase[j + 1];
  cntA[t] = 0;
  cntB[t] = 0;
  __syncthreads();
  for (int e = e0 + t; e < e1; e += 256)
    atomicAdd(&cntA[epair[e] & 255], 1);
  __syncthreads();
  int deg = cntA[t];
  ps[t] = deg;
  __syncthreads();
  #pragma unroll
  for (int off = 1; off < 256; off <<= 1) {
    int u = (t >= off) ? ps[t - off] : 0;
    __syncthreads();
    ps[t] += u;
    __syncthreads();
  }
  rpl[t] = e0 + ps[t] - deg;
  __syncthreads();
  int node = node0 + t;
  if (node < NN) {
    rp[node] = rpl[t];
    ds[node] = rsqrtf(fmaxf((float)deg, 1.0f));
  }
  if (j == 0 && t == 0) { rp[NN] = EE; ds[NN] = 0.f; }  // ds[NN]=0 zeroes sentinel gathers
  for (int e = e0 + t; e < e1; e += 256) {
    u32 pv = epair[e];
    int d = pv & 255;
    int pos = rpl[d] + atomicAdd(&cntB[d], 1);
    esrc[pos] = (int)(pv >> 8);
  }
}

// ---------------- prep: X0b table + folded Wf ----------------
// h = X0(W0-W2) + X1*W1 + Z*(-2*W2), Z = ds*sum(ds*X1)  -> fold into Wf phases.
__global__ void k_prep(const float* __restrict__ feature,
                       u32* __restrict__ X0b,
                       const float* __restrict__ W, u32* __restrict__ Wf) {
  int i = blockIdx.x * blockDim.x + threadIdx.x;
  if (i < 96 * 256) {
    // Wf u32 index = ((phase*4+ks)*8+nj)*256 + lane*4 + j
    int fi = i >> 8;
    int lane = (i >> 2) & 63;
    int jj = i & 3;
    int phase = fi >> 5, ks = (fi >> 3) & 3, nj = fi & 7;
    int g = lane >> 4, l15 = lane & 15;
    int nn = nj * 16 + l15;
    int ku = phase * 64 + ks * 16 + g * 4 + jj;
    int k = ku * 2;
    float a0 = W[(size_t)k * 128 + nn];
    float a1 = W[(size_t)(k + 1) * 128 + nn];
    if (phase == 0) {
      a0 -= W[(size_t)(k + 256) * 128 + nn];
      a1 -= W[(size_t)(k + 257) * 128 + nn];
    } else if (phase == 2) {
      a0 *= -2.0f;
      a1 *= -2.0f;
    }
    Wf[i] = pack_bf2(a0, a1);
  }
  const int total = NN * 32;  // uint2 count (4 dims each)
  int st = gridDim.x * blockDim.x;
  for (int j = i; j < total; j += st) {
    int n = j >> 5;
    float4 f = *(const float4*)(feature + (size_t)n * DIM + (j & 31) * 4);
    ((uint2*)X0b)[j] = make_uint2(pack_bf2(f.x, f.y), pack_bf2(f.z, f.w));
  }
}

// ---------------- prop1: X1 = -ds[n]*sum ds[s]*X0[s] ----------------
// Wide gather (dwordx4/lane, 4 edges per wave-instruction), sentinel-select
// tails (ds[NN]=0), shfl_xor combine. Props at random-gather request-BW floor
// (~410MB @ ~6.7TB/s request-side) -- bracketed R8-R10.
__global__ __launch_bounds__(256) void k_prop1(const u32* __restrict__ X0b,
                                               const float* __restrict__ ds,
                                               const int* __restrict__ rp,
                                               const int* __restrict__ esrc,
                                               u32* __restrict__ X1b) {
  int n = blockIdx.x * 4 + (threadIdx.x >> 6);
  int lane = threadIdx.x & 63;
  int grp = lane >> 4, l15 = lane & 15;
  int beg = rp[n], end = rp[n + 1];
  float axA[4], ayA[4], axB[4], ayB[4];
  #pragma unroll
  for (int i = 0; i < 4; ++i) { axA[i] = 0.f; ayA[i] = 0.f; axB[i] = 0.f; ayB[i] = 0.f; }
  for (int p = beg; p < end; p += 8) {
    int qA = p + grp, qB = p + 4 + grp;
    int evA = esrc[qA];            // unconditional (esrc padded)
    int evB = esrc[qB];
    int sA = (qA < end) ? evA : NN;  // register select, no branch
    int sB = (qB < end) ? evB : NN;
    uint4 uA = *(const uint4*)(X0b + (size_t)sA * 64 + l15 * 4);
    uint4 uB = *(const uint4*)(X0b + (size_t)sB * 64 + l15 * 4);
    float dvA = ds[sA];
    float dvB = ds[sB];
    axA[0] = fmaf(lof(uA.x), dvA, axA[0]); ayA[0] = fmaf(hif(uA.x), dvA, ayA[0]);
    axA[1] = fmaf(lof(uA.y), dvA, axA[1]); ayA[1] = fmaf(hif(uA.y), dvA, ayA[1]);
    axA[2] = fmaf(lof(uA.z), dvA, axA[2]); ayA[2] = fmaf(hif(uA.z), dvA, ayA[2]);
    axA[3] = fmaf(lof(uA.w), dvA, axA[3]); ayA[3] = fmaf(hif(uA.w), dvA, ayA[3]);
    axB[0] = fmaf(lof(uB.x), dvB, axB[0]); ayB[0] = fmaf(hif(uB.x), dvB, ayB[0]);
    axB[1] = fmaf(lof(uB.y), dvB, axB[1]); ayB[1] = fmaf(hif(uB.y), dvB, ayB[1]);
    axB[2] = fmaf(lof(uB.z), dvB, axB[2]); ayB[2] = fmaf(hif(uB.z), dvB, ayB[2]);
    axB[3] = fmaf(lof(uB.w), dvB, axB[3]); ayB[3] = fmaf(hif(uB.w), dvB, ayB[3]);
  }
  float v[8];
  #pragma unroll
  for (int i = 0; i < 4; ++i) {
    v[2 * i] = axA[i] + axB[i];
    v[2 * i + 1] = ayA[i] + ayB[i];
  }
  #pragma unroll
  for (int i = 0; i < 8; ++i) {
    v[i] += __shfl_xor(v[i], 16);
    v[i] += __shfl_xor(v[i], 32);
  }
  if (grp == 0) {
    float dsn = ds[n];
    uint4 o;
    o.x = pack_bf2(-dsn * v[0], -dsn * v[1]);
    o.y = pack_bf2(-dsn * v[2], -dsn * v[3]);
    o.z = pack_bf2(-dsn * v[4], -dsn * v[5]);
    o.w = pack_bf2(-dsn * v[6], -dsn * v[7]);
    *(uint4*)(X1b + (size_t)n * 64 + l15 * 4) = o;
  }
}

// ---------------- prop2: Z = ds[n]*sum X1[s]*ds[s] (X0-term folded into Wf) ----
__global__ __launch_bounds__(256) void k_prop2(const u32* __restrict__ X1b,
                                               const float* __restrict__ ds,
                                               const int* __restrict__ rp,
                                               const int* __restrict__ esrc,
                                               u32* __restrict__ Zb) {
  int n = blockIdx.x * 4 + (threadIdx.x >> 6);
  int lane = threadIdx.x & 63;
  int grp = lane >> 4, l15 = lane & 15;
  int beg = rp[n], end = rp[n + 1];
  float axA[4], ayA[4], axB[4], ayB[4];
  #pragma unroll
  for (int i = 0; i < 4; ++i) { axA[i] = 0.f; ayA[i] = 0.f; axB[i] = 0.f; ayB[i] = 0.f; }
  for (int p = beg; p < end; p += 8) {
    int qA = p + grp, qB = p + 4 + grp;
    int evA = esrc[qA];
    int evB = esrc[qB];
    int sA = (qA < end) ? evA : NN;
    int sB = (qB < end) ? evB : NN;
    uint4 uA = *(const uint4*)(X1b + (size_t)sA * 64 + l15 * 4);
    uint4 uB = *(const uint4*)(X1b + (size_t)sB * 64 + l15 * 4);
    float dvA = ds[sA];
    float dvB = ds[sB];
    axA[0] = fmaf(lof(uA.x), dvA, axA[0]); ayA[0] = fmaf(hif(uA.x), dvA, ayA[0]);
    axA[1] = fmaf(lof(uA.y), dvA, axA[1]); ayA[1] = fmaf(hif(uA.y), dvA, ayA[1]);
    axA[2] = fmaf(lof(uA.z), dvA, axA[2]); ayA[2] = fmaf(hif(uA.z), dvA, ayA[2]);
    axA[3] = fmaf(lof(uA.w), dvA, axA[3]); ayA[3] = fmaf(hif(uA.w), dvA, ayA[3]);
    axB[0] = fmaf(lof(uB.x), dvB, axB[0]); ayB[0] = fmaf(hif(uB.x), dvB, ayB[0]);
    axB[1] = fmaf(lof(uB.y), dvB, axB[1]); ayB[1] = fmaf(hif(uB.y), dvB, ayB[1]);
    axB[2] = fmaf(lof(uB.z), dvB, axB[2]); ayB[2] = fmaf(hif(uB.z), dvB, ayB[2]);
    axB[3] = fmaf(lof(uB.w), dvB, axB[3]); ayB[3] = fmaf(hif(uB.w), dvB, ayB[3]);
  }
  float v[8];
  #pragma unroll
  for (int i = 0; i < 4; ++i) {
    v[2 * i] = axA[i] + axB[i];
    v[2 * i + 1] = ayA[i] + ayB[i];
  }
  #pragma unroll
  for (int i = 0; i < 8; ++i) {
    v[i] += __shfl_xor(v[i], 16);
    v[i] += __shfl_xor(v[i], 32);
  }
  if (grp == 0) {
    float dsn = ds[n];
    uint4 o;
    o.x = pack_bf2(dsn * v[0], dsn * v[1]);
    o.y = pack_bf2(dsn * v[2], dsn * v[3]);
    o.z = pack_bf2(dsn * v[4], dsn * v[5]);
    o.w = pack_bf2(dsn * v[6], dsn * v[7]);
    *(uint4*)(Zb + (size_t)n * 64 + l15 * 4) = o;
  }
}

// ---------------- MFMA GEMM: 1024 thr, 96KB Wf staged once; bf16 h out ----
// h stored bf16 into the X0b region: each wave reads/writes ONLY its own
// 32-row slab (rb0/rb1 and epilogue rows are wave-private), and the phase-0
// X0b loads feed the acc used by the store -> data dependence orders them.
__global__ __launch_bounds__(1024) void k_gemm(const u32* __restrict__ X0b,
                                               const u32* __restrict__ X1b,
                                               const u32* __restrict__ Zb,
                                               const u32* __restrict__ Wf,
                                               const float* __restrict__ bias,
                                               const float* __restrict__ snorm,
                                               u16* __restrict__ Hb,
                                               float* __restrict__ gsum_part,
                                               float* __restrict__ gsq_part) {
  __shared__ u32 wlds[24576];   // 96 KB
  __shared__ float ls[256];
  int tid = threadIdx.x;
  #pragma unroll
  for (int l = 0; l < 6; ++l) {
    int it = tid + l * 1024;
    ((uint4*)wlds)[it] = ((const uint4*)Wf)[it];
  }
  int wid = tid >> 6, lane = tid & 63;
  int l15 = lane & 15, g = lane >> 4;
  int row0 = blockIdx.x * 512 + wid * 32;
  bool active = (row0 + 32) <= NN;
  if (!active) row0 = 0;

  size_t rb0 = (size_t)(row0 + l15) * 64 + g * 4;
  size_t rb1 = rb0 + (size_t)16 * 64;

  f32x4 acc[2][8];
  #pragma unroll
  for (int mi = 0; mi < 2; ++mi)
    #pragma unroll
    for (int nj = 0; nj < 8; ++nj) acc[mi][nj] = (f32x4){0.f, 0.f, 0.f, 0.f};

  __syncthreads();

  const u32* tabs[3] = {X0b, X1b, Zb};
  #pragma unroll
  for (int phase = 0; phase < 3; ++phase) {
    const u32* A = tabs[phase];
    #pragma unroll
    for (int ks = 0; ks < 4; ++ks) {
      U4 a0, a1;
      a0.u = *(const uint4*)(A + rb0 + ks * 16);
      a1.u = *(const uint4*)(A + rb1 + ks * 16);
      #pragma unroll
      for (int nj = 0; nj < 8; ++nj) {
        U4 b;
        b.u = ((const uint4*)wlds)[((phase * 4 + ks) * 8 + nj) * 64 + lane];
        acc[0][nj] = __builtin_amdgcn_mfma_f32_16x16x32_bf16(a0.h, b.h, acc[0][nj], 0, 0, 0);
        acc[1][nj] = __builtin_amdgcn_mfma_f32_16x16x32_bf16(a1.h, b.h, acc[1][nj], 0, 0, 0);
      }
    }
  }

  float cs[8], cq[8];
  #pragma unroll
  for (int nj = 0; nj < 8; ++nj) { cs[nj] = 0.f; cq[nj] = 0.f; }
  if (active) {
    float bs[8];
    #pragma unroll
    for (int nj = 0; nj < 8; ++nj) bs[nj] = bias[nj * 16 + l15];
    #pragma unroll
    for (int mi = 0; mi < 2; ++mi) {
      #pragma unroll
      for (int r = 0; r < 4; ++r) {
        int row = row0 + mi * 16 + g * 4 + r;
        float sn = snorm[row];
        #pragma unroll
        for (int nj = 0; nj < 8; ++nj) {
          float h = (acc[mi][nj][r] + bs[nj]) * sn;
          Hb[(size_t)row * DIM + nj * 16 + l15] = (u16)pack_bf2(h, 0.f);
          cs[nj] += h;
          cq[nj] += h * h;
        }
      }
    }
  }
  if (tid < 256) ls[tid] = 0.f;
  __syncthreads();
  if (active) {
    #pragma unroll
    for (int nj = 0; nj < 8; ++nj) {
      atomicAdd(&ls[nj * 16 + l15], cs[nj]);      // LDS atomics only
      atomicAdd(&ls[128 + nj * 16 + l15], cq[nj]);
    }
  }
  __syncthreads();
  if (tid < 128) {  // plain stores -- no global atomics
    gsum_part[(size_t)blockIdx.x * 128 + tid] = ls[tid];
    gsq_part[(size_t)blockIdx.x * 128 + tid] = ls[128 + tid];
  }
}

// ---------------- reduce partials -> scale/shift ----------------
__global__ __launch_bounds__(128) void k_bnprep(const float* __restrict__ gsum_part,
                                                const float* __restrict__ gsq_part,
                                                const float* __restrict__ gamma,
                                                const float* __restrict__ beta,
                                                float* __restrict__ scale,
                                                float* __restrict__ shift) {
  int c = threadIdx.x;
  float s = 0.f, q = 0.f;
  for (int j = 0; j < GBLK; ++j) {
    s += gsum_part[(size_t)j * 128 + c];
    q += gsq_part[(size_t)j * 128 + c];
  }
  float m = s * (1.0f / NN);
  float var = fmaxf(q * (1.0f / NN) - m * m, 0.f);
  float sc = gamma[c] * rsqrtf(var + 1e-5f);
  scale[c] = sc;
  shift[c] = beta[c] - m * sc;
}

// ---------------- BN apply + relu: read bf16 h, write f32 out ----------------
__global__ __launch_bounds__(256) void k_apply(const u16* __restrict__ Hb,
                                               float* __restrict__ out,
                                               const float* __restrict__ scale,
                                               const float* __restrict__ shift) {
  const int total4 = NN * DIM / 4;
  int i = blockIdx.x * blockDim.x + threadIdx.x;
  int st = gridDim.x * blockDim.x;   // multiple of 32 -> (i&31) invariant
  int c4 = (i & 31) * 4;
  float4 s = *(const float4*)(scale + c4);
  float4 sh = *(const float4*)(shift + c4);
  for (int i4 = i; i4 < total4; i4 += st) {
    uint2 hv = ((const uint2*)Hb)[i4];
    float4 v = make_float4(lof(hv.x), hif(hv.x), lof(hv.y), hif(hv.y));
    v.x = fmaxf(fmaf(v.x, s.x, sh.x), 0.f);
    v.y = fmaxf(fmaf(v.y, s.y, sh.y), 0.f);
    v.z = fmaxf(fmaf(v.z, s.z, sh.z), 0.f);
    v.w = fmaxf(fmaf(v.w, s.w, sh.w), 0.f);
    ((float4*)out)[i4] = v;
  }
}

extern "C" void kernel_launch(void* const* d_in, const int* in_sizes, int n_in,
                              void* d_out, int out_size, void* d_ws, size_t ws_size,
                              hipStream_t stream) {
  const float* feature = (const float*)d_in[0];
  const float* snorm   = (const float*)d_in[1];
  const int*   src     = (const int*)d_in[2];
  const int*   dst     = (const int*)d_in[3];
  const float* W       = (const float*)d_in[4];
  const float* bias    = (const float*)d_in[5];
  const float* gamma   = (const float*)d_in[6];
  const float* beta    = (const float*)d_in[7];
  float* out = (float*)d_out;

  const size_t TBL = (size_t)(NN + 1) * 64 * sizeof(u32);  // 25.6 MB + sentinel row
  char* p = (char*)d_ws;
  u32* X0b = (u32*)p; p += TBL;   // also reused as bf16 Hb by k_gemm epilogue
  u32* X1b = (u32*)p; p += TBL;   // epair (6.4 MB) aliases this until k_fine done
  u32* Zb  = (u32*)p; p += TBL;
  u32* epair = (u32*)X1b;
  u16* Hb = (u16*)X0b;
  u32* Wf  = (u32*)p; p += 96 * 256 * sizeof(u32);   // 98.3 KB
  int* esrc = (int*)p;    p += (size_t)(EE + 16) * 4;  // padded for batch OOB reads
  int* rp   = (int*)p;    p += ((size_t)(NN + 1) * 4 + 127) & ~(size_t)127;
  float* ds = (float*)p;  p += (size_t)(NN + 1) * 4;
  int* hist_t   = (int*)p; p += (size_t)NBUCK * B1 * 4;  // 200 KB
  int* blockoff = (int*)p; p += (size_t)NBUCK * B1 * 4;  // 200 KB
  int* btot  = (int*)p;   p += 512 * 4;
  int* bbase = (int*)p;   p += 512 * 4;
  float* gsum_part = (float*)p; p += (size_t)GBLK * 128 * 4;  // 100 KB
  float* gsq_part  = (float*)p; p += (size_t)GBLK * 128 * 4;  // 100 KB
  float* scale = (float*)p; p += 512;
  float* shift = (float*)p; p += 512;

  k_hist<<<B1, 256, 0, stream>>>(dst, hist_t);
  k_boff<<<NBUCK, B1, 0, stream>>>(hist_t, blockoff, btot);
  k_bbase<<<1, 512, 0, stream>>>(btot, bbase);
  k_bucket<<<B1, 256, 0, stream>>>(src, dst, bbase, blockoff, epair);
  k_fine<<<NBUCK, 256, 0, stream>>>(epair, bbase, rp, ds, esrc);
  k_prep<<<4096, 256, 0, stream>>>(feature, X0b, W, Wf);
  k_prop1<<<NN / 4, 256, 0, stream>>>(X0b, ds, rp, esrc, X1b);
  k_prop2<<<NN / 4, 256, 0, stream>>>(X1b, ds, rp, esrc, Zb);
  k_gemm<<<GBLK, 1024, 0, stream>>>(X0b, X1b, Zb, Wf, bias, snorm, Hb,
                                    gsum_part, gsq_part);
  k_bnprep<<<1, 128, 0, stream>>>(gsum_part, gsq_part, gamma, beta, scale, shift);
  k_apply<<<4096, 256, 0, stream>>>(Hb, out, scale, shift);
}

// Round 16
// 251.284 us; speedup vs baseline: 1.1482x; 1.0168x over previous
//
#include <hip/hip_runtime.h>

#define NN 100000
#define EE 1600000
#define DIM 128
#define NBUCK ((NN + 255) >> 8)   // 391 buckets of 256 nodes
#define B1 128                    // bucket-pass blocks
#define CH ((EE + B1 - 1) / B1)   // 12500 edges per block
#define GBLK ((NN + 511) / 512)   // 196 gemm blocks (1024 thr, 512 rows each)
#define FBLK 4096                 // prep-role blocks in k_front

typedef unsigned int u32;
typedef unsigned short u16;
typedef __attribute__((ext_vector_type(8))) short bf16x8;
typedef __attribute__((ext_vector_type(4))) float f32x4;

union U4 { uint4 u; bf16x8 h; };

__device__ __forceinline__ float lof(u32 u) { return __uint_as_float(u << 16); }
__device__ __forceinline__ float hif(u32 u) { return __uint_as_float(u & 0xffff0000u); }
__device__ __forceinline__ u32 pack_bf2(float a, float b) {
  u32 ua = __float_as_uint(a), ub = __float_as_uint(b);
  ua = (ua + 0x7fffu + ((ua >> 16) & 1u)) >> 16;
  ub = (ub + 0x7fffu + ((ub >> 16) & 1u)) & 0xffff0000u;
  return ua | ub;
}

// ---------------- fused front: hist role (blocks 0..B1-1) + prep role ----------------
// hist and prep are fully independent; co-scheduling hides prep's ~13us behind
// the CSR chain's first pass instead of serializing it.
__global__ __launch_bounds__(256) void k_front(const int* __restrict__ dst,
                                               int* __restrict__ hist_t,
                                               const float* __restrict__ feature,
                                               u32* __restrict__ X0b,
                                               const float* __restrict__ W,
                                               u32* __restrict__ Wf) {
  if (blockIdx.x < B1) {
    __shared__ int h[NBUCK];
    for (int i = threadIdx.x; i < NBUCK; i += 256) h[i] = 0;
    __syncthreads();
    int e0 = blockIdx.x * CH;
    int e1 = e0 + CH < EE ? e0 + CH : EE;
    for (int e = e0 + threadIdx.x; e < e1; e += 256)
      atomicAdd(&h[dst[e] >> 8], 1);
    __syncthreads();
    for (int i = threadIdx.x; i < NBUCK; i += 256)
      hist_t[i * B1 + blockIdx.x] = h[i];
  } else {
    int i = (blockIdx.x - B1) * 256 + threadIdx.x;
    if (i < 96 * 256) {
      // Wf u32 index = ((phase*4+ks)*8+nj)*256 + lane*4 + j
      // h = X0(W0-W2) + X1*W1 + Z*(-2*W2), Z = ds*sum(ds*X1) -> folded phases.
      int fi = i >> 8;
      int lane = (i >> 2) & 63;
      int jj = i & 3;
      int phase = fi >> 5, ks = (fi >> 3) & 3, nj = fi & 7;
      int g = lane >> 4, l15 = lane & 15;
      int nn = nj * 16 + l15;
      int ku = phase * 64 + ks * 16 + g * 4 + jj;
      int k = ku * 2;
      float a0 = W[(size_t)k * 128 + nn];
      float a1 = W[(size_t)(k + 1) * 128 + nn];
      if (phase == 0) {
        a0 -= W[(size_t)(k + 256) * 128 + nn];
        a1 -= W[(size_t)(k + 257) * 128 + nn];
      } else if (phase == 2) {
        a0 *= -2.0f;
        a1 *= -2.0f;
      }
      Wf[i] = pack_bf2(a0, a1);
    }
    const int total = NN * 32;  // uint2 count (4 dims each)
    const int st = FBLK * 256;
    for (int j = i; j < total; j += st) {
      int n = j >> 5;
      float4 f = *(const float4*)(feature + (size_t)n * DIM + (j & 31) * 4);
      ((uint2*)X0b)[j] = make_uint2(pack_bf2(f.x, f.y), pack_bf2(f.z, f.w));
    }
  }
}

// ---------------- pass B: per-bucket scan over blocks ----------------
__global__ __launch_bounds__(B1) void k_boff(const int* __restrict__ hist_t,
                                             int* __restrict__ blockoff,
                                             int* __restrict__ btot) {
  __shared__ int ps[B1];
  int j = blockIdx.x, t = threadIdx.x;
  int v = hist_t[j * B1 + t];
  ps[t] = v;
  __syncthreads();
  #pragma unroll
  for (int off = 1; off < B1; off <<= 1) {
    int u = (t >= off) ? ps[t - off] : 0;
    __syncthreads();
    ps[t] += u;
    __syncthreads();
  }
  blockoff[j * B1 + t] = ps[t] - v;
  if (t == B1 - 1) btot[j] = ps[t];
}

// ---------------- pass B2: scan bucket totals -> bbase ----------------
__global__ __launch_bounds__(512) void k_bbase(const int* __restrict__ btot,
                                               int* __restrict__ bbase) {
  __shared__ int ps[512];
  int t = threadIdx.x;
  int v = (t < NBUCK) ? btot[t] : 0;
  ps[t] = v;
  __syncthreads();
  #pragma unroll
  for (int off = 1; off < 512; off <<= 1) {
    int u = (t >= off) ? ps[t - off] : 0;
    __syncthreads();
    ps[t] += u;
    __syncthreads();
  }
  if (t < NBUCK) bbase[t] = ps[t] - v;
  if (t == 0) bbase[NBUCK] = EE;
}

// ---------------- pass C: scatter packed (src<<8|dlow) into bucket regions ----------------
__global__ __launch_bounds__(256) void k_bucket(const int* __restrict__ src,
                                                const int* __restrict__ dst,
                                                const int* __restrict__ bbase,
                                                const int* __restrict__ blockoff,
                                                u32* __restrict__ epair) {
  __shared__ int cnt[NBUCK];
  for (int i = threadIdx.x; i < NBUCK; i += 256) cnt[i] = 0;
  __syncthreads();
  int e0 = blockIdx.x * CH;
  int e1 = e0 + CH < EE ? e0 + CH : EE;
  for (int e = e0 + threadIdx.x; e < e1; e += 256) {
    int d = dst[e], s = src[e];
    int j = d >> 8;
    int loc = atomicAdd(&cnt[j], 1);
    epair[bbase[j] + blockoff[j * B1 + blockIdx.x] + loc] =
        ((u32)s << 8) | (u32)(d & 255);
  }
}

// ---------------- pass D: per-bucket deg/ds/rp + fine scatter -> esrc ----------------
__global__ __launch_bounds__(256) void k_fine(const u32* __restrict__ epair,
                                              const int* __restrict__ bbase,
                                              int* __restrict__ rp,
                                              float* __restrict__ ds,
                                              int* __restrict__ esrc) {
  __shared__ int cntA[256], cntB[256], rpl[256], ps[256];
  int j = blockIdx.x, t = threadIdx.x;
  int node0 = j << 8;
  int e0 = bbase[j], e1 = bbase[j + 1];
  cntA[t] = 0;
  cntB[t] = 0;
  __syncthreads();
  for (int e = e0 + t; e < e1; e += 256)
    atomicAdd(&cntA[epair[e] & 255], 1);
  __syncthreads();
  int deg = cntA[t];
  ps[t] = deg;
  __syncthreads();
  #pragma unroll
  for (int off = 1; off < 256; off <<= 1) {
    int u = (t >= off) ? ps[t - off] : 0;
    __syncthreads();
    ps[t] += u;
    __syncthreads();
  }
  rpl[t] = e0 + ps[t] - deg;
  __syncthreads();
  int node = node0 + t;
  if (node < NN) {
    rp[node] = rpl[t];
    ds[node] = rsqrtf(fmaxf((float)deg, 1.0f));
  }
  if (j == 0 && t == 0) { rp[NN] = EE; ds[NN] = 0.f; }  // ds[NN]=0 zeroes sentinel gathers
  for (int e = e0 + t; e < e1; e += 256) {
    u32 pv = epair[e];
    int d = pv & 255;
    int pos = rpl[d] + atomicAdd(&cntB[d], 1);
    esrc[pos] = (int)(pv >> 8);
  }
}

// ---------------- prop1: X1 = -ds[n]*sum ds[s]*X0[s] ----------------
// Wide gather (dwordx4/lane, 4 edges per wave-instruction), sentinel-select
// tails (ds[NN]=0), shfl_xor combine. Props at random-gather request-BW floor
// (~410MB @ ~6.7TB/s request-side) -- bracketed R8-R10.
__global__ __launch_bounds__(256) void k_prop1(const u32* __restrict__ X0b,
                                               const float* __restrict__ ds,
                                               const int* __restrict__ rp,
                                               const int* __restrict__ esrc,
                                               u32* __restrict__ X1b) {
  int n = blockIdx.x * 4 + (threadIdx.x >> 6);
  int lane = threadIdx.x & 63;
  int grp = lane >> 4, l15 = lane & 15;
  int beg = rp[n], end = rp[n + 1];
  float axA[4], ayA[4], axB[4], ayB[4];
  #pragma unroll
  for (int i = 0; i < 4; ++i) { axA[i] = 0.f; ayA[i] = 0.f; axB[i] = 0.f; ayB[i] = 0.f; }
  for (int p = beg; p < end; p += 8) {
    int qA = p + grp, qB = p + 4 + grp;
    int evA = esrc[qA];            // unconditional (esrc padded)
    int evB = esrc[qB];
    int sA = (qA < end) ? evA : NN;  // register select, no branch
    int sB = (qB < end) ? evB : NN;
    uint4 uA = *(const uint4*)(X0b + (size_t)sA * 64 + l15 * 4);
    uint4 uB = *(const uint4*)(X0b + (size_t)sB * 64 + l15 * 4);
    float dvA = ds[sA];
    float dvB = ds[sB];
    axA[0] = fmaf(lof(uA.x), dvA, axA[0]); ayA[0] = fmaf(hif(uA.x), dvA, ayA[0]);
    axA[1] = fmaf(lof(uA.y), dvA, axA[1]); ayA[1] = fmaf(hif(uA.y), dvA, ayA[1]);
    axA[2] = fmaf(lof(uA.z), dvA, axA[2]); ayA[2] = fmaf(hif(uA.z), dvA, ayA[2]);
    axA[3] = fmaf(lof(uA.w), dvA, axA[3]); ayA[3] = fmaf(hif(uA.w), dvA, ayA[3]);
    axB[0] = fmaf(lof(uB.x), dvB, axB[0]); ayB[0] = fmaf(hif(uB.x), dvB, ayB[0]);
    axB[1] = fmaf(lof(uB.y), dvB, axB[1]); ayB[1] = fmaf(hif(uB.y), dvB, ayB[1]);
    axB[2] = fmaf(lof(uB.z), dvB, axB[2]); ayB[2] = fmaf(hif(uB.z), dvB, ayB[2]);
    axB[3] = fmaf(lof(uB.w), dvB, axB[3]); ayB[3] = fmaf(hif(uB.w), dvB, ayB[3]);
  }
  float v[8];
  #pragma unroll
  for (int i = 0; i < 4; ++i) {
    v[2 * i] = axA[i] + axB[i];
    v[2 * i + 1] = ayA[i] + ayB[i];
  }
  #pragma unroll
  for (int i = 0; i < 8; ++i) {
    v[i] += __shfl_xor(v[i], 16);
    v[i] += __shfl_xor(v[i], 32);
  }
  if (grp == 0) {
    float dsn = ds[n];
    uint4 o;
    o.x = pack_bf2(-dsn * v[0], -dsn * v[1]);
    o.y = pack_bf2(-dsn * v[2], -dsn * v[3]);
    o.z = pack_bf2(-dsn * v[4], -dsn * v[5]);
    o.w = pack_bf2(-dsn * v[6], -dsn * v[7]);
    *(uint4*)(X1b + (size_t)n * 64 + l15 * 4) = o;
  }
}

// ---------------- prop2: Z = ds[n]*sum X1[s]*ds[s] (X0-term folded into Wf) ----
__global__ __launch_bounds__(256) void k_prop2(const u32* __restrict__ X1b,
                                               const float* __restrict__ ds,
                                               const int* __restrict__ rp,
                                               const int* __restrict__ esrc,
                                               u32* __restrict__ Zb) {
  int n = blockIdx.x * 4 + (threadIdx.x >> 6);
  int lane = threadIdx.x & 63;
  int grp = lane >> 4, l15 = lane & 15;
  int beg = rp[n], end = rp[n + 1];
  float axA[4], ayA[4], axB[4], ayB[4];
  #pragma unroll
  for (int i = 0; i < 4; ++i) { axA[i] = 0.f; ayA[i] = 0.f; axB[i] = 0.f; ayB[i] = 0.f; }
  for (int p = beg; p < end; p += 8) {
    int qA = p + grp, qB = p + 4 + grp;
    int evA = esrc[qA];
    int evB = esrc[qB];
    int sA = (qA < end) ? evA : NN;
    int sB = (qB < end) ? evB : NN;
    uint4 uA = *(const uint4*)(X1b + (size_t)sA * 64 + l15 * 4);
    uint4 uB = *(const uint4*)(X1b + (size_t)sB * 64 + l15 * 4);
    float dvA = ds[sA];
    float dvB = ds[sB];
    axA[0] = fmaf(lof(uA.x), dvA, axA[0]); ayA[0] = fmaf(hif(uA.x), dvA, ayA[0]);
    axA[1] = fmaf(lof(uA.y), dvA, axA[1]); ayA[1] = fmaf(hif(uA.y), dvA, ayA[1]);
    axA[2] = fmaf(lof(uA.z), dvA, axA[2]); ayA[2] = fmaf(hif(uA.z), dvA, ayA[2]);
    axA[3] = fmaf(lof(uA.w), dvA, axA[3]); ayA[3] = fmaf(hif(uA.w), dvA, ayA[3]);
    axB[0] = fmaf(lof(uB.x), dvB, axB[0]); ayB[0] = fmaf(hif(uB.x), dvB, ayB[0]);
    axB[1] = fmaf(lof(uB.y), dvB, axB[1]); ayB[1] = fmaf(hif(uB.y), dvB, ayB[1]);
    axB[2] = fmaf(lof(uB.z), dvB, axB[2]); ayB[2] = fmaf(hif(uB.z), dvB, ayB[2]);
    axB[3] = fmaf(lof(uB.w), dvB, axB[3]); ayB[3] = fmaf(hif(uB.w), dvB, ayB[3]);
  }
  float v[8];
  #pragma unroll
  for (int i = 0; i < 4; ++i) {
    v[2 * i] = axA[i] + axB[i];
    v[2 * i + 1] = ayA[i] + ayB[i];
  }
  #pragma unroll
  for (int i = 0; i < 8; ++i) {
    v[i] += __shfl_xor(v[i], 16);
    v[i] += __shfl_xor(v[i], 32);
  }
  if (grp == 0) {
    float dsn = ds[n];
    uint4 o;
    o.x = pack_bf2(dsn * v[0], dsn * v[1]);
    o.y = pack_bf2(dsn * v[2], dsn * v[3]);
    o.z = pack_bf2(dsn * v[4], dsn * v[5]);
    o.w = pack_bf2(dsn * v[6], dsn * v[7]);
    *(uint4*)(Zb + (size_t)n * 64 + l15 * 4) = o;
  }
}

// ---------------- MFMA GEMM: 1024 thr, 96KB Wf staged once; bf16 h out ----
// h stored bf16 into the X0b region: each wave reads/writes ONLY its own
// 32-row slab (rb0/rb1 and epilogue rows are wave-private), and the phase-0
// X0b loads feed the acc used by the store -> data dependence orders them.
__global__ __launch_bounds__(1024) void k_gemm(const u32* __restrict__ X0b,
                                               const u32* __restrict__ X1b,
                                               const u32* __restrict__ Zb,
                                               const u32* __restrict__ Wf,
                                               const float* __restrict__ bias,
                                               const float* __restrict__ snorm,
                                               u16* __restrict__ Hb,
                                               float* __restrict__ gsum_part,
                                               float* __restrict__ gsq_part) {
  __shared__ u32 wlds[24576];   // 96 KB
  __shared__ float ls[256];
  int tid = threadIdx.x;
  #pragma unroll
  for (int l = 0; l < 6; ++l) {
    int it = tid + l * 1024;
    ((uint4*)wlds)[it] = ((const uint4*)Wf)[it];
  }
  int wid = tid >> 6, lane = tid & 63;
  int l15 = lane & 15, g = lane >> 4;
  int row0 = blockIdx.x * 512 + wid * 32;
  bool active = (row0 + 32) <= NN;
  if (!active) row0 = 0;

  size_t rb0 = (size_t)(row0 + l15) * 64 + g * 4;
  size_t rb1 = rb0 + (size_t)16 * 64;

  f32x4 acc[2][8];
  #pragma unroll
  for (int mi = 0; mi < 2; ++mi)
    #pragma unroll
    for (int nj = 0; nj < 8; ++nj) acc[mi][nj] = (f32x4){0.f, 0.f, 0.f, 0.f};

  __syncthreads();

  const u32* tabs[3] = {X0b, X1b, Zb};
  #pragma unroll
  for (int phase = 0; phase < 3; ++phase) {
    const u32* A = tabs[phase];
    #pragma unroll
    for (int ks = 0; ks < 4; ++ks) {
      U4 a0, a1;
      a0.u = *(const uint4*)(A + rb0 + ks * 16);
      a1.u = *(const uint4*)(A + rb1 + ks * 16);
      #pragma unroll
      for (int nj = 0; nj < 8; ++nj) {
        U4 b;
        b.u = ((const uint4*)wlds)[((phase * 4 + ks) * 8 + nj) * 64 + lane];
        acc[0][nj] = __builtin_amdgcn_mfma_f32_16x16x32_bf16(a0.h, b.h, acc[0][nj], 0, 0, 0);
        acc[1][nj] = __builtin_amdgcn_mfma_f32_16x16x32_bf16(a1.h, b.h, acc[1][nj], 0, 0, 0);
      }
    }
  }

  float cs[8], cq[8];
  #pragma unroll
  for (int nj = 0; nj < 8; ++nj) { cs[nj] = 0.f; cq[nj] = 0.f; }
  if (active) {
    float bs[8];
    #pragma unroll
    for (int nj = 0; nj < 8; ++nj) bs[nj] = bias[nj * 16 + l15];
    #pragma unroll
    for (int mi = 0; mi < 2; ++mi) {
      #pragma unroll
      for (int r = 0; r < 4; ++r) {
        int row = row0 + mi * 16 + g * 4 + r;
        float sn = snorm[row];
        #pragma unroll
        for (int nj = 0; nj < 8; ++nj) {
          float h = (acc[mi][nj][r] + bs[nj]) * sn;
          Hb[(size_t)row * DIM + nj * 16 + l15] = (u16)pack_bf2(h, 0.f);
          cs[nj] += h;
          cq[nj] += h * h;
        }
      }
    }
  }
  if (tid < 256) ls[tid] = 0.f;
  __syncthreads();
  if (active) {
    #pragma unroll
    for (int nj = 0; nj < 8; ++nj) {
      atomicAdd(&ls[nj * 16 + l15], cs[nj]);      // LDS atomics only
      atomicAdd(&ls[128 + nj * 16 + l15], cq[nj]);
    }
  }
  __syncthreads();
  if (tid < 128) {  // plain stores -- no global atomics
    gsum_part[(size_t)blockIdx.x * 128 + tid] = ls[tid];
    gsq_part[(size_t)blockIdx.x * 128 + tid] = ls[128 + tid];
  }
}

// ---------------- reduce partials -> scale/shift ----------------
__global__ __launch_bounds__(128) void k_bnprep(const float* __restrict__ gsum_part,
                                                const float* __restrict__ gsq_part,
                                                const float* __restrict__ gamma,
                                                const float* __restrict__ beta,
                                                float* __restrict__ scale,
                                                float* __restrict__ shift) {
  int c = threadIdx.x;
  float s = 0.f, q = 0.f;
  for (int j = 0; j < GBLK; ++j) {
    s += gsum_part[(size_t)j * 128 + c];
    q += gsq_part[(size_t)j * 128 + c];
  }
  float m = s * (1.0f / NN);
  float var = fmaxf(q * (1.0f / NN) - m * m, 0.f);
  float sc = gamma[c] * rsqrtf(var + 1e-5f);
  scale[c] = sc;
  shift[c] = beta[c] - m * sc;
}

// ---------------- BN apply + relu: read bf16 h, write f32 out ----------------
__global__ __launch_bounds__(256) void k_apply(const u16* __restrict__ Hb,
                                               float* __restrict__ out,
                                               const float* __restrict__ scale,
                                               const float* __restrict__ shift) {
  const int total4 = NN * DIM / 4;
  int i = blockIdx.x * blockDim.x + threadIdx.x;
  int st = gridDim.x * blockDim.x;   // multiple of 32 -> (i&31) invariant
  int c4 = (i & 31) * 4;
  float4 s = *(const float4*)(scale + c4);
  float4 sh = *(const float4*)(shift + c4);
  for (int i4 = i; i4 < total4; i4 += st) {
    uint2 hv = ((const uint2*)Hb)[i4];
    float4 v = make_float4(lof(hv.x), hif(hv.x), lof(hv.y), hif(hv.y));
    v.x = fmaxf(fmaf(v.x, s.x, sh.x), 0.f);
    v.y = fmaxf(fmaf(v.y, s.y, sh.y), 0.f);
    v.z = fmaxf(fmaf(v.z, s.z, sh.z), 0.f);
    v.w = fmaxf(fmaf(v.w, s.w, sh.w), 0.f);
    ((float4*)out)[i4] = v;
  }
}

extern "C" void kernel_launch(void* const* d_in, const int* in_sizes, int n_in,
                              void* d_out, int out_size, void* d_ws, size_t ws_size,
                              hipStream_t stream) {
  const float* feature = (const float*)d_in[0];
  const float* snorm   = (const float*)d_in[1];
  const int*   src     = (const int*)d_in[2];
  const int*   dst     = (const int*)d_in[3];
  const float* W       = (const float*)d_in[4];
  const float* bias    = (const float*)d_in[5];
  const float* gamma   = (const float*)d_in[6];
  const float* beta    = (const float*)d_in[7];
  float* out = (float*)d_out;

  const size_t TBL = (size_t)(NN + 1) * 64 * sizeof(u32);  // 25.6 MB + sentinel row
  char* p = (char*)d_ws;
  u32* X0b = (u32*)p; p += TBL;   // also reused as bf16 Hb by k_gemm epilogue
  u32* X1b = (u32*)p; p += TBL;   // epair (6.4 MB) aliases this until k_fine done
  u32* Zb  = (u32*)p; p += TBL;
  u32* epair = (u32*)X1b;
  u16* Hb = (u16*)X0b;
  u32* Wf  = (u32*)p; p += 96 * 256 * sizeof(u32);   // 98.3 KB
  int* esrc = (int*)p;    p += (size_t)(EE + 16) * 4;  // padded for batch OOB reads
  int* rp   = (int*)p;    p += ((size_t)(NN + 1) * 4 + 127) & ~(size_t)127;
  float* ds = (float*)p;  p += (size_t)(NN + 1) * 4;
  int* hist_t   = (int*)p; p += (size_t)NBUCK * B1 * 4;  // 200 KB
  int* blockoff = (int*)p; p += (size_t)NBUCK * B1 * 4;  // 200 KB
  int* btot  = (int*)p;   p += 512 * 4;
  int* bbase = (int*)p;   p += 512 * 4;
  float* gsum_part = (float*)p; p += (size_t)GBLK * 128 * 4;  // 100 KB
  float* gsq_part  = (float*)p; p += (size_t)GBLK * 128 * 4;  // 100 KB
  float* scale = (float*)p; p += 512;
  float* shift = (float*)p; p += 512;

  k_front<<<B1 + FBLK, 256, 0, stream>>>(dst, hist_t, feature, X0b, W, Wf);
  k_boff<<<NBUCK, B1, 0, stream>>>(hist_t, blockoff, btot);
  k_bbase<<<1, 512, 0, stream>>>(btot, bbase);
  k_bucket<<<B1, 256, 0, stream>>>(src, dst, bbase, blockoff, epair);
  k_fine<<<NBUCK, 256, 0, stream>>>(epair, bbase, rp, ds, esrc);
  k_prop1<<<NN / 4, 256, 0, stream>>>(X0b, ds, rp, esrc, X1b);
  k_prop2<<<NN / 4, 256, 0, stream>>>(X1b, ds, rp, esrc, Zb);
  k_gemm<<<GBLK, 1024, 0, stream>>>(X0b, X1b, Zb, Wf, bias, snorm, Hb,
                                    gsum_part, gsq_part);
  k_bnprep<<<1, 128, 0, stream>>>(gsum_part, gsq_part, gamma, beta, scale, shift);
  k_apply<<<4096, 256, 0, stream>>>(Hb, out, scale, shift);
}